// Round 16
// baseline (619.493 us; speedup 1.0000x reference)
//
#include <hip/hip_runtime.h>
#include <stdint.h>
#include <stddef.h>

// Pipeline:
//  k_wt     : W -> Wt fp16 [1024][256] (transposed)
//  k_init   : denom=num=0, deg=cursor=0, pooled=0
//  k_count  : deg[dst]++ over edges
//  k_scan1/2/3 : exclusive scan of deg -> rowstart[n+1]  (CSR offsets)
//  k_gemm   : 256 thr / 4 waves, BLK_M=128, B strips of 32 cols dbuf in LDS
//             (2x16KB = 32KB -> 4 blocks/CU = 16 waves/CU; round-15's 8-wave
//             BLK_M=256 blew L3: FETCH 54->232MB. Keep per-block footprint,
//             raise blocks/CU instead). f16 MFMA; A frags in regs; xw fp16.
//  k_denom  : p=exp(lrelu(a_s[src]+a_d[dst])); denom/num atomics; CSR scatter
//             MERGED: pos=rowstart[dst]+cursor++, csr_src[pos]=src, pe_csr[pos]=p.
//  k_pool2  : pooled[h] = sum_dst num/denom
//  k_head   : head gate a4 + fused bias hb
//  k_fuse   : per node (1 wave): CSR loop, (j,pv) prefetched 1 ahead. h fp16.
//  k_out    : per edge (1 wave): log_softmax((h[s]*h[d]) @ linW + b)

typedef _Float16 f16x8 __attribute__((ext_vector_type(8)));
typedef float f32x4 __attribute__((ext_vector_type(4)));
typedef unsigned short u16x8 __attribute__((ext_vector_type(8)));
typedef unsigned short u16x4 __attribute__((ext_vector_type(4)));

__device__ __forceinline__ unsigned short f2h(float f) {
  _Float16 h = (_Float16)f;
  return __builtin_bit_cast(unsigned short, h);
}
__device__ __forceinline__ float h2f(unsigned short s) {
  return (float)__builtin_bit_cast(_Float16, s);
}
__device__ __forceinline__ float lrelu(float v) { return v >= 0.f ? v : 0.2f * v; }

__device__ __forceinline__ void gload16(const void* g, void* l) {
  __builtin_amdgcn_global_load_lds((const __attribute__((address_space(1))) void*)g,
                                   (__attribute__((address_space(3))) void*)l, 16, 0, 0);
}

// ---------------- weight transpose ----------------
__global__ __launch_bounds__(256) void k_wt(const float* __restrict__ W,
                                            unsigned short* __restrict__ wt) {
  int idx = blockIdx.x * 256 + threadIdx.x;
  int m = idx >> 8, k = idx & 255;
  wt[idx] = f2h(W[(size_t)k * 1024 + m]);
}

// ---------------- init ----------------
__global__ __launch_bounds__(256) void k_init(float* __restrict__ denom, float* __restrict__ num,
                                              int* __restrict__ deg, int* __restrict__ cursor,
                                              float* __restrict__ pooled, int n) {
  int i = blockIdx.x * 256 + threadIdx.x;
  if (i < n * 4) {
    denom[i] = 0.f;
    num[i] = 0.f;
  }
  if (i < n) { deg[i] = 0; cursor[i] = 0; }
  if (i < 4) pooled[i] = 0.f;
}

// ---------------- CSR build ----------------
__global__ __launch_bounds__(256) void k_count(const int* __restrict__ ei, int* __restrict__ deg, int E) {
  int e = blockIdx.x * 256 + threadIdx.x;
  if (e < E) atomicAdd(&deg[ei[E + e]], 1);
}

__global__ __launch_bounds__(256) void k_scan1(const int* __restrict__ deg, int* __restrict__ pre,
                                               int* __restrict__ bsum, int n) {
  int t = threadIdx.x, b = blockIdx.x;
  int i = b * 256 + t;
  int v = (i < n) ? deg[i] : 0;
  int lane = t & 63, w = t >> 6;
  int incl = v;
#pragma unroll
  for (int o = 1; o < 64; o <<= 1) {
    int u = __shfl_up(incl, o);
    if (lane >= o) incl += u;
  }
  __shared__ int ws[4];
  if (lane == 63) ws[w] = incl;
  __syncthreads();
  int add = 0;
  for (int k = 0; k < w; ++k) add += ws[k];
  int excl = incl - v + add;
  if (i < n) pre[i] = excl;
  if (t == 255) bsum[b] = excl + v;
}

__global__ __launch_bounds__(256) void k_scan2(const int* __restrict__ bsum, int* __restrict__ bsumx, int nb) {
  __shared__ int s[2][512];
  int t = threadIdx.x;
#pragma unroll
  for (int k = 0; k < 2; ++k) {
    int i = t + 256 * k;
    s[0][i] = (i < nb) ? bsum[i] : 0;
  }
  __syncthreads();
  int src = 0;
  for (int off = 1; off < 512; off <<= 1) {
#pragma unroll
    for (int k = 0; k < 2; ++k) {
      int i = t + 256 * k;
      int v = s[src][i];
      if (i >= off) v += s[src][i - off];
      s[src ^ 1][i] = v;
    }
    __syncthreads();
    src ^= 1;
  }
#pragma unroll
  for (int k = 0; k < 2; ++k) {
    int i = t + 256 * k;
    if (i < nb) bsumx[i] = s[src][i] - bsum[i];
  }
}

__global__ __launch_bounds__(256) void k_scan3(const int* __restrict__ pre, const int* __restrict__ bsumx,
                                               int* __restrict__ rowstart, int n, int E) {
  int i = blockIdx.x * 256 + threadIdx.x;
  if (i < n) rowstart[i] = pre[i] + bsumx[blockIdx.x];
  if (i == 0) rowstart[n] = E;
}

// ---------------- GEMM: xw = x @ W (f16 MFMA), 4 waves, 32-col strips ----------------
__global__ __launch_bounds__(256, 4) void k_gemm(const float* __restrict__ X,
                                                 const unsigned short* __restrict__ Bt,
                                                 const float* __restrict__ att_s_g,
                                                 const float* __restrict__ att_d_g,
                                                 unsigned short* __restrict__ C,
                                                 float* __restrict__ a_s, float* __restrict__ a_d,
                                                 float* __restrict__ s_row,
                                                 int NR) {
  __shared__ unsigned short Bs[2][32 * 256];  // 2 x 16 KB
  const int t = threadIdx.x;
  const int w = t >> 6, lane = t & 63;
  const int kc = lane >> 4, rl = lane & 15;
  const int row0 = blockIdx.x * 128 + w * 32;

  f16x8 aF[2][8];
#pragma unroll
  for (int mi = 0; mi < 2; ++mi) {
    const int ar = min(row0 + mi * 16 + rl, NR - 1);
#pragma unroll
    for (int kk = 0; kk < 8; ++kk) {
      const float* xp = X + (size_t)ar * 256 + kk * 32 + kc * 8;
      float4 lo = *(const float4*)xp;
      float4 hi = *(const float4*)(xp + 4);
      f16x8 v;
      v[0] = (_Float16)lo.x; v[1] = (_Float16)lo.y;
      v[2] = (_Float16)lo.z; v[3] = (_Float16)lo.w;
      v[4] = (_Float16)hi.x; v[5] = (_Float16)hi.y;
      v[6] = (_Float16)hi.z; v[7] = (_Float16)hi.w;
      aF[mi][kk] = v;
    }
  }

  // stage strip 0: 32 rows x 32 chunk16 = 1024 chunks over 256 threads -> 4 iters
#pragma unroll
  for (int i = 0; i < 4; ++i) {
    int idx = i * 256 + t;
    int r = idx >> 5, c = idx & 31;
    gload16(Bt + (size_t)r * 256 + ((c ^ (r & 15)) << 3),
            &Bs[0][(size_t)(i * 256 + w * 64) * 8]);
  }
  __syncthreads();

  float as_run[2][4], ad_run[2][4], sr_run[2][4];
#pragma unroll
  for (int mi = 0; mi < 2; ++mi)
#pragma unroll
    for (int j = 0; j < 4; ++j) { as_run[mi][j] = 0.f; ad_run[mi][j] = 0.f; sr_run[mi][j] = 0.f; }

#pragma unroll 1
  for (int hn = 0; hn < 32; ++hn) {
    const int cb0 = hn * 32;
    const int cur = hn & 1;
    if (hn < 31) {
#pragma unroll
      for (int i = 0; i < 4; ++i) {
        int idx = i * 256 + t;
        int r = idx >> 5, c = idx & 31;
        gload16(Bt + (size_t)(cb0 + 32 + r) * 256 + ((c ^ (r & 15)) << 3),
                &Bs[cur ^ 1][(size_t)(i * 256 + w * 64) * 8]);
      }
    }

    f32x4 acc[2][2];
#pragma unroll
    for (int mi = 0; mi < 2; ++mi)
#pragma unroll
      for (int ni = 0; ni < 2; ++ni) acc[mi][ni] = (f32x4){0.f, 0.f, 0.f, 0.f};

#pragma unroll
    for (int kk = 0; kk < 8; ++kk) {
      f16x8 bF[2];
#pragma unroll
      for (int ni = 0; ni < 2; ++ni)
        bF[ni] = *(const f16x8*)&Bs[cur][(ni * 16 + rl) * 256 + (((kk * 4 + kc) ^ rl) << 3)];
#pragma unroll
      for (int mi = 0; mi < 2; ++mi)
#pragma unroll
        for (int ni = 0; ni < 2; ++ni)
          acc[mi][ni] = __builtin_amdgcn_mfma_f32_16x16x32_f16(aF[mi][kk], bF[ni], acc[mi][ni], 0, 0, 0);
    }

    float asv[2], adv[2];
#pragma unroll
    for (int ni = 0; ni < 2; ++ni) {
      asv[ni] = att_s_g[cb0 + ni * 16 + rl];
      adv[ni] = att_d_g[cb0 + ni * 16 + rl];
    }
#pragma unroll
    for (int mi = 0; mi < 2; ++mi)
#pragma unroll
      for (int j = 0; j < 4; ++j) {
        int row = row0 + mi * 16 + kc * 4 + j;
        bool ok = row < NR;
        float ps = 0.f, pd = 0.f, pr = 0.f;
#pragma unroll
        for (int ni = 0; ni < 2; ++ni) {
          float v = acc[mi][ni][j];
          ps += v * asv[ni];
          pd += v * adv[ni];
          pr += v;
          if (ok) C[(size_t)row * 1024 + cb0 + ni * 16 + rl] = f2h(v);
        }
        as_run[mi][j] += ps; ad_run[mi][j] += pd; sr_run[mi][j] += pr;
      }
    // head boundary: 8 strips per head
    if ((hn & 7) == 7) {
      const int h = hn >> 3;
#pragma unroll
      for (int mi = 0; mi < 2; ++mi)
#pragma unroll
        for (int j = 0; j < 4; ++j) {
          float ps = as_run[mi][j], pd = ad_run[mi][j], pr = sr_run[mi][j];
#pragma unroll
          for (int o = 1; o <= 8; o <<= 1) {
            ps += __shfl_xor(ps, o);
            pd += __shfl_xor(pd, o);
            pr += __shfl_xor(pr, o);
          }
          if (rl == 0) {
            int row = row0 + mi * 16 + kc * 4 + j;
            if (row < NR) {
              a_s[(size_t)row * 4 + h] = ps;
              a_d[(size_t)row * 4 + h] = pd;
              s_row[(size_t)row * 4 + h] = pr;
            }
          }
          as_run[mi][j] = 0.f; ad_run[mi][j] = 0.f; sr_run[mi][j] = 0.f;
        }
    }
    __syncthreads();
  }
}

// ---------------- per-edge denom + numerator + CSR scatter (merged) ----------------
__global__ __launch_bounds__(256) void k_denom(const int* __restrict__ ei, const int* __restrict__ rowstart,
                                               int* __restrict__ cursor,
                                               const float* __restrict__ a_s, const float* __restrict__ a_d,
                                               const float* __restrict__ s_row,
                                               float* __restrict__ denom, float* __restrict__ num,
                                               float* __restrict__ pe_csr, float* __restrict__ pe_self,
                                               int* __restrict__ csr_src,
                                               int E, int n) {
  int e = blockIdx.x * 256 + threadIdx.x;
  int tot = E + n;
  if (e >= tot) return;
  int src = e < E ? ei[e] : (e - E);
  int dst = e < E ? ei[E + e] : (e - E);
  float asv[4], adv[4], sv[4], pv[4];
  *(float4*)asv = *(const float4*)(a_s + (size_t)src * 4);
  *(float4*)adv = *(const float4*)(a_d + (size_t)dst * 4);
  *(float4*)sv = *(const float4*)(s_row + (size_t)src * 4);
#pragma unroll
  for (int h = 0; h < 4; ++h) {
    float p = expf(lrelu(asv[h] + adv[h]));
    pv[h] = p;
    atomicAdd(&denom[(size_t)dst * 4 + h], p);
    atomicAdd(&num[(size_t)dst * 4 + h], p * sv[h]);
  }
  if (e < E) {
    int pos = rowstart[dst] + atomicAdd(&cursor[dst], 1);
    csr_src[pos] = src;
    *(float4*)(pe_csr + (size_t)pos * 4) = *(float4*)pv;
  } else {
    *(float4*)(pe_self + (size_t)(e - E) * 4) = *(float4*)pv;
  }
}

// ---------------- pooled[h] = sum_dst num/denom ----------------
__global__ __launch_bounds__(256) void k_pool2(const float* __restrict__ denom,
                                               const float* __restrict__ num,
                                               float* __restrict__ pooled, int n) {
  float ph[4] = {0.f, 0.f, 0.f, 0.f};
  for (int i = blockIdx.x * 256 + threadIdx.x; i < n; i += gridDim.x * 256) {
    float4 dv = *(const float4*)(denom + (size_t)i * 4);
    float4 nv = *(const float4*)(num + (size_t)i * 4);
    ph[0] += nv.x / (dv.x + 1e-16f);
    ph[1] += nv.y / (dv.y + 1e-16f);
    ph[2] += nv.z / (dv.z + 1e-16f);
    ph[3] += nv.w / (dv.w + 1e-16f);
  }
  int w = threadIdx.x >> 6, lane = threadIdx.x & 63;
#pragma unroll
  for (int h = 0; h < 4; ++h)
#pragma unroll
    for (int o = 32; o >= 1; o >>= 1) ph[h] += __shfl_xor(ph[h], o);
  __shared__ float red[4][4];
  if (lane == 0) {
#pragma unroll
    for (int h = 0; h < 4; ++h) red[w][h] = ph[h];
  }
  __syncthreads();
  if (threadIdx.x == 0) {
#pragma unroll
    for (int h = 0; h < 4; ++h)
      atomicAdd(&pooled[h], red[0][h] + red[1][h] + red[2][h] + red[3][h]);
  }
}

// ---------------- head gate + fused bias ----------------
__global__ __launch_bounds__(256) void k_head(const float* __restrict__ pooled,
                                              const float* __restrict__ gbias,
                                              const float* __restrict__ cw, const float* __restrict__ cb,
                                              float* __restrict__ a4, float* __restrict__ hb, int n) {
  __shared__ float red[4][4];
  __shared__ float aa[4];
  int t = threadIdx.x, w = t >> 6, lane = t & 63;
#pragma unroll
  for (int h = 0; h < 4; ++h) {
    float v = gbias[h * 256 + t];
#pragma unroll
    for (int o = 32; o >= 1; o >>= 1) v += __shfl_xor(v, o);
    if (lane == 0) red[h][w] = v;
  }
  __syncthreads();
  if (t == 0) {
    float q[4], mx = -1e30f;
    for (int h = 0; h < 4; ++h) {
      float bm = (red[h][0] + red[h][1] + red[h][2] + red[h][3]) * (1.f / 256.f);
      float pl = pooled[h] / ((float)n * 256.f) + bm;
      float c = pl * cw[0] + cb[0];
      c = fmaxf(c, 0.f);
      q[h] = c;
      mx = fmaxf(mx, c);
    }
    float sum = 0.f;
    for (int h = 0; h < 4; ++h) { q[h] = expf(q[h] - mx); sum += q[h]; }
    for (int h = 0; h < 4; ++h) { aa[h] = q[h] / sum; a4[h] = aa[h]; }
  }
  __syncthreads();
  float hbv = 0.f;
  for (int h = 0; h < 4; ++h) hbv += aa[h] * gbias[h * 256 + t];
  hb[t] = hbv;
}

// ---------------- per-node fused aggregation -> h (fp16 out), CSR ----------------
__global__ __launch_bounds__(256) void k_fuse(const int* __restrict__ rowstart,
                                              const int* __restrict__ csr_src,
                                              const unsigned short* __restrict__ xwh,
                                              const float* __restrict__ pe_csr,
                                              const float* __restrict__ pe_self,
                                              const float* __restrict__ denom,
                                              const float* __restrict__ a4, const float* __restrict__ hb,
                                              const float* __restrict__ x, unsigned short* __restrict__ hbuf,
                                              int n) {
  int node = blockIdx.x * 4 + (threadIdx.x >> 6);
  int lane = threadIdx.x & 63;
  if (node >= n) return;
  float dv[4], av[4], avinv[4];
  *(float4*)dv = *(const float4*)(denom + (size_t)node * 4);
  *(float4*)av = *(const float4*)a4;
#pragma unroll
  for (int h = 0; h < 4; ++h) avinv[h] = av[h] / (dv[h] + 1e-16f);
  float acc0 = 0.f, acc1 = 0.f, acc2 = 0.f, acc3 = 0.f;
  const int c0 = lane * 4;

  {
    float pv[4];
    *(float4*)pv = *(const float4*)(pe_self + (size_t)node * 4);
    float ws[4];
#pragma unroll
    for (int h = 0; h < 4; ++h) ws[h] = avinv[h] * pv[h];
    const unsigned short* rp = xwh + (size_t)node * 1024;
#pragma unroll
    for (int h = 0; h < 4; ++h) {
      u16x4 q = *(const u16x4*)(rp + h * 256 + c0);
      acc0 += ws[h] * h2f(q[0]);
      acc1 += ws[h] * h2f(q[1]);
      acc2 += ws[h] * h2f(q[2]);
      acc3 += ws[h] * h2f(q[3]);
    }
  }

  const int s0 = rowstart[node], s1 = rowstart[node + 1];
  int i = s0;
  int jn = 0;
  float4 pvn = {0.f, 0.f, 0.f, 0.f};
  if (i < s1) {
    jn = csr_src[i];
    pvn = *(const float4*)(pe_csr + (size_t)i * 4);
  }
  while (i < s1) {
    int j = jn;
    float4 pv4 = pvn;
    int i2 = i + 1;
    if (i2 < s1) {
      jn = csr_src[i2];
      pvn = *(const float4*)(pe_csr + (size_t)i2 * 4);
    }
    float ws[4];
    ws[0] = avinv[0] * pv4.x; ws[1] = avinv[1] * pv4.y;
    ws[2] = avinv[2] * pv4.z; ws[3] = avinv[3] * pv4.w;
    const unsigned short* rp = xwh + (size_t)j * 1024;
#pragma unroll
    for (int h = 0; h < 4; ++h) {
      u16x4 q = *(const u16x4*)(rp + h * 256 + c0);
      acc0 += ws[h] * h2f(q[0]);
      acc1 += ws[h] * h2f(q[1]);
      acc2 += ws[h] * h2f(q[2]);
      acc3 += ws[h] * h2f(q[3]);
    }
    i = i2;
  }
  float4 xb = *(const float4*)(x + (size_t)node * 256 + c0);
  float4 hbv = *(const float4*)(hb + c0);
  u16x4 o;
  o[0] = f2h(fmaxf(acc0 + hbv.x + xb.x, 0.f));
  o[1] = f2h(fmaxf(acc1 + hbv.y + xb.y, 0.f));
  o[2] = f2h(fmaxf(acc2 + hbv.z + xb.z, 0.f));
  o[3] = f2h(fmaxf(acc3 + hbv.w + xb.w, 0.f));
  *(u16x4*)(hbuf + (size_t)node * 256 + c0) = o;
}

// ---------------- edge classifier + log_softmax (fp16 gather) ----------------
__global__ __launch_bounds__(256) void k_out(const int* __restrict__ ei,
                                             const unsigned short* __restrict__ hbuf,
                                             const float* __restrict__ linW, const float* __restrict__ linb,
                                             float* __restrict__ out, int E) {
  int gw = blockIdx.x * 4 + (threadIdx.x >> 6);
  int lane = threadIdx.x & 63;
  if (gw >= E) return;
  int src = ei[gw], dst = ei[E + gw];
  const int c0 = lane * 4;
  u16x4 qs = *(const u16x4*)(hbuf + (size_t)src * 256 + c0);
  u16x4 qd = *(const u16x4*)(hbuf + (size_t)dst * 256 + c0);
  float4 wa = *(const float4*)(linW + (size_t)c0 * 2);
  float4 wb = *(const float4*)(linW + (size_t)c0 * 2 + 4);
  float e0 = h2f(qs[0]) * h2f(qd[0]);
  float e1 = h2f(qs[1]) * h2f(qd[1]);
  float e2 = h2f(qs[2]) * h2f(qd[2]);
  float e3 = h2f(qs[3]) * h2f(qd[3]);
  float u0 = e0 * wa.x + e1 * wa.z + e2 * wb.x + e3 * wb.z;
  float u1 = e0 * wa.y + e1 * wa.w + e2 * wb.y + e3 * wb.w;
#pragma unroll
  for (int o = 32; o >= 1; o >>= 1) {
    u0 += __shfl_xor(u0, o);
    u1 += __shfl_xor(u1, o);
  }
  if (lane == 0) {
    u0 += linb[0];
    u1 += linb[1];
    float mx = fmaxf(u0, u1);
    float lse = mx + logf(expf(u0 - mx) + expf(u1 - mx));
    float2 r;
    r.x = u0 - lse;
    r.y = u1 - lse;
    *(float2*)(out + (size_t)gw * 2) = r;
  }
}

// ---------------- launch ----------------
extern "C" void kernel_launch(void* const* d_in, const int* in_sizes, int n_in,
                              void* d_out, int out_size, void* d_ws, size_t ws_size,
                              hipStream_t stream) {
  const float* x = (const float*)d_in[0];
  const int* ei = (const int*)d_in[1];
  const float* W = (const float*)d_in[2];
  const float* att_s_g = (const float*)d_in[3];
  const float* att_d_g = (const float*)d_in[4];
  const float* gbias = (const float*)d_in[5];
  const float* cw = (const float*)d_in[6];
  const float* cb = (const float*)d_in[7];
  const float* linW = (const float*)d_in[8];
  const float* linb = (const float*)d_in[9];
  float* out = (float*)d_out;

  const int n = in_sizes[0] / 256;   // 100000
  const int E = in_sizes[1] / 2;     // 300000
  const int tot = E + n;
  const int nb = (n + 255) / 256;

  char* p = (char*)d_ws;
  auto alloc = [&](size_t bytes) -> char* {
    char* r = p;
    p += (bytes + 255) & ~(size_t)255;
    return r;
  };
  unsigned short* xwh = (unsigned short*)alloc((size_t)n * 1024 * 2);
  unsigned short* wth = (unsigned short*)alloc((size_t)1024 * 256 * 2);
  float* a_s = (float*)alloc((size_t)n * 4 * 4);
  float* a_d = (float*)alloc((size_t)n * 4 * 4);
  float* s_row = (float*)alloc((size_t)n * 4 * 4);
  float* denom = (float*)alloc((size_t)n * 4 * 4);
  float* num = (float*)alloc((size_t)n * 4 * 4);
  float* pe_csr = (float*)alloc((size_t)E * 4 * 4);
  float* pe_self = (float*)alloc((size_t)n * 4 * 4);
  int* deg = (int*)alloc((size_t)n * 4);
  int* cursor = (int*)alloc((size_t)n * 4);
  int* pre = (int*)alloc((size_t)n * 4);
  int* bsum = (int*)alloc(512 * 4);
  int* bsumx = (int*)alloc(512 * 4);
  int* rowstart = (int*)alloc((size_t)(n + 1) * 4);
  int* csr_src = (int*)alloc((size_t)E * 4);
  float* pooled = (float*)alloc(256);
  float* a4 = (float*)alloc(256);
  float* hb = (float*)alloc(256 * 4);
  unsigned short* hbuf = (unsigned short*)alloc((size_t)n * 256 * 2);

  k_wt<<<dim3(1024), dim3(256), 0, stream>>>(W, wth);
  k_init<<<dim3((n * 4 + 255) / 256), dim3(256), 0, stream>>>(denom, num, deg, cursor, pooled, n);
  k_count<<<dim3((E + 255) / 256), dim3(256), 0, stream>>>(ei, deg, E);
  k_scan1<<<dim3(nb), dim3(256), 0, stream>>>(deg, pre, bsum, n);
  k_scan2<<<dim3(1), dim3(256), 0, stream>>>(bsum, bsumx, nb);
  k_scan3<<<dim3(nb), dim3(256), 0, stream>>>(pre, bsumx, rowstart, n, E);
  k_gemm<<<dim3((n + 127) / 128), dim3(256), 0, stream>>>(x, wth, att_s_g, att_d_g, xwh, a_s, a_d, s_row, n);
  k_denom<<<dim3((tot + 255) / 256), dim3(256), 0, stream>>>(ei, rowstart, cursor, a_s, a_d, s_row, denom, num, pe_csr, pe_self, csr_src, E, n);
  k_pool2<<<dim3(64), dim3(256), 0, stream>>>(denom, num, pooled, n);
  k_head<<<dim3(1), dim3(256), 0, stream>>>(pooled, gbias, cw, cb, a4, hb, n);
  k_fuse<<<dim3((n + 3) / 4), dim3(256), 0, stream>>>(rowstart, csr_src, xwh, pe_csr, pe_self, denom, a4, hb, x, hbuf, n);
  k_out<<<dim3((E + 3) / 4), dim3(256), 0, stream>>>(ei, hbuf, linW, linb, out, E);
}

// Round 17
// 513.844 us; speedup vs baseline: 1.2056x; 1.2056x over previous
//
#include <hip/hip_runtime.h>
#include <stdint.h>
#include <stddef.h>

// Pipeline:
//  k_wt     : W -> Wt fp16 [1024][256] (transposed)
//  k_init   : denom=num=0, deg=cursor=0, pooled=0
//  k_count  : deg[dst]++ over edges
//  k_scan1/2/3 : exclusive scan of deg -> rowstart[n+1]  (CSR offsets)
//  k_gemm   : 256 thr / 4 waves, BLK_M=128, B strips of 64 cols dbuf in LDS
//             (2x32KB). ROUND-14 CONFIG, verified 143us. R15 (8 waves/BLK_M=256)
//             and R16 (32-col strips, 4 blk/CU) both regressed: more concurrent
//             blocks thrash L3 (FETCH 54->141/232MB) and narrow strips fragment
//             C stores (WRITE 262->315MB). 17% occ is BOUGHT by X L3-residency.
//  k_denom  : p=exp(lrelu(a_s[src]+a_d[dst])); denom/num atomics; CSR scatter
//             merged: pos=rowstart[dst]+cursor++, csr_src[pos]=src, pe_csr[pos]=p.
//  k_pool2  : pooled[h] = sum_dst num/denom
//  k_head   : head gate a4 + fused bias hb
//  k_fuse   : per node (1 wave): CSR loop, (j,pv) prefetched 1 ahead. h fp16.
//  k_out    : per edge (1 wave): log_softmax((h[s]*h[d]) @ linW + b)

typedef _Float16 f16x8 __attribute__((ext_vector_type(8)));
typedef float f32x4 __attribute__((ext_vector_type(4)));
typedef unsigned short u16x8 __attribute__((ext_vector_type(8)));
typedef unsigned short u16x4 __attribute__((ext_vector_type(4)));

__device__ __forceinline__ unsigned short f2h(float f) {
  _Float16 h = (_Float16)f;
  return __builtin_bit_cast(unsigned short, h);
}
__device__ __forceinline__ float h2f(unsigned short s) {
  return (float)__builtin_bit_cast(_Float16, s);
}
__device__ __forceinline__ float lrelu(float v) { return v >= 0.f ? v : 0.2f * v; }

__device__ __forceinline__ void gload16(const void* g, void* l) {
  __builtin_amdgcn_global_load_lds((const __attribute__((address_space(1))) void*)g,
                                   (__attribute__((address_space(3))) void*)l, 16, 0, 0);
}

// ---------------- weight transpose ----------------
__global__ __launch_bounds__(256) void k_wt(const float* __restrict__ W,
                                            unsigned short* __restrict__ wt) {
  int idx = blockIdx.x * 256 + threadIdx.x;
  int m = idx >> 8, k = idx & 255;
  wt[idx] = f2h(W[(size_t)k * 1024 + m]);
}

// ---------------- init ----------------
__global__ __launch_bounds__(256) void k_init(float* __restrict__ denom, float* __restrict__ num,
                                              int* __restrict__ deg, int* __restrict__ cursor,
                                              float* __restrict__ pooled, int n) {
  int i = blockIdx.x * 256 + threadIdx.x;
  if (i < n * 4) {
    denom[i] = 0.f;
    num[i] = 0.f;
  }
  if (i < n) { deg[i] = 0; cursor[i] = 0; }
  if (i < 4) pooled[i] = 0.f;
}

// ---------------- CSR build ----------------
__global__ __launch_bounds__(256) void k_count(const int* __restrict__ ei, int* __restrict__ deg, int E) {
  int e = blockIdx.x * 256 + threadIdx.x;
  if (e < E) atomicAdd(&deg[ei[E + e]], 1);
}

__global__ __launch_bounds__(256) void k_scan1(const int* __restrict__ deg, int* __restrict__ pre,
                                               int* __restrict__ bsum, int n) {
  int t = threadIdx.x, b = blockIdx.x;
  int i = b * 256 + t;
  int v = (i < n) ? deg[i] : 0;
  int lane = t & 63, w = t >> 6;
  int incl = v;
#pragma unroll
  for (int o = 1; o < 64; o <<= 1) {
    int u = __shfl_up(incl, o);
    if (lane >= o) incl += u;
  }
  __shared__ int ws[4];
  if (lane == 63) ws[w] = incl;
  __syncthreads();
  int add = 0;
  for (int k = 0; k < w; ++k) add += ws[k];
  int excl = incl - v + add;
  if (i < n) pre[i] = excl;
  if (t == 255) bsum[b] = excl + v;
}

__global__ __launch_bounds__(256) void k_scan2(const int* __restrict__ bsum, int* __restrict__ bsumx, int nb) {
  __shared__ int s[2][512];
  int t = threadIdx.x;
#pragma unroll
  for (int k = 0; k < 2; ++k) {
    int i = t + 256 * k;
    s[0][i] = (i < nb) ? bsum[i] : 0;
  }
  __syncthreads();
  int src = 0;
  for (int off = 1; off < 512; off <<= 1) {
#pragma unroll
    for (int k = 0; k < 2; ++k) {
      int i = t + 256 * k;
      int v = s[src][i];
      if (i >= off) v += s[src][i - off];
      s[src ^ 1][i] = v;
    }
    __syncthreads();
    src ^= 1;
  }
#pragma unroll
  for (int k = 0; k < 2; ++k) {
    int i = t + 256 * k;
    if (i < nb) bsumx[i] = s[src][i] - bsum[i];
  }
}

__global__ __launch_bounds__(256) void k_scan3(const int* __restrict__ pre, const int* __restrict__ bsumx,
                                               int* __restrict__ rowstart, int n, int E) {
  int i = blockIdx.x * 256 + threadIdx.x;
  if (i < n) rowstart[i] = pre[i] + bsumx[blockIdx.x];
  if (i == 0) rowstart[n] = E;
}

// ---------------- GEMM: xw = x @ W (f16 MFMA), R14 config ----------------
__global__ __launch_bounds__(256, 2) void k_gemm(const float* __restrict__ X,
                                                 const unsigned short* __restrict__ Bt,
                                                 const float* __restrict__ att_s_g,
                                                 const float* __restrict__ att_d_g,
                                                 unsigned short* __restrict__ C,
                                                 float* __restrict__ a_s, float* __restrict__ a_d,
                                                 float* __restrict__ s_row,
                                                 int NR) {
  __shared__ unsigned short Bs[2][64 * 256];  // 2 x 32 KB
  const int t = threadIdx.x;
  const int w = t >> 6, lane = t & 63;
  const int kc = lane >> 4, rl = lane & 15;
  const int row0 = blockIdx.x * 128 + w * 32;

  f16x8 aF[2][8];
#pragma unroll
  for (int mi = 0; mi < 2; ++mi) {
    const int ar = min(row0 + mi * 16 + rl, NR - 1);
#pragma unroll
    for (int kk = 0; kk < 8; ++kk) {
      const float* xp = X + (size_t)ar * 256 + kk * 32 + kc * 8;
      float4 lo = *(const float4*)xp;
      float4 hi = *(const float4*)(xp + 4);
      f16x8 v;
      v[0] = (_Float16)lo.x; v[1] = (_Float16)lo.y;
      v[2] = (_Float16)lo.z; v[3] = (_Float16)lo.w;
      v[4] = (_Float16)hi.x; v[5] = (_Float16)hi.y;
      v[6] = (_Float16)hi.z; v[7] = (_Float16)hi.w;
      aF[mi][kk] = v;
    }
  }

#pragma unroll
  for (int i = 0; i < 8; ++i) {
    int idx = i * 256 + t;
    int r = idx >> 5, c = idx & 31;
    gload16(Bt + (size_t)r * 256 + ((c ^ (r & 15)) << 3),
            &Bs[0][(size_t)(i * 256 + w * 64) * 8]);
  }
  __syncthreads();

  float as_run[2][4], ad_run[2][4], sr_run[2][4];
#pragma unroll
  for (int mi = 0; mi < 2; ++mi)
#pragma unroll
    for (int j = 0; j < 4; ++j) { as_run[mi][j] = 0.f; ad_run[mi][j] = 0.f; sr_run[mi][j] = 0.f; }

#pragma unroll 1
  for (int hn = 0; hn < 16; ++hn) {
    const int cb0 = hn * 64;
    const int cur = hn & 1;
    if (hn < 15) {
#pragma unroll
      for (int i = 0; i < 8; ++i) {
        int idx = i * 256 + t;
        int r = idx >> 5, c = idx & 31;
        gload16(Bt + (size_t)(cb0 + 64 + r) * 256 + ((c ^ (r & 15)) << 3),
                &Bs[cur ^ 1][(size_t)(i * 256 + w * 64) * 8]);
      }
    }

    f32x4 acc[2][4];
#pragma unroll
    for (int mi = 0; mi < 2; ++mi)
#pragma unroll
      for (int ni = 0; ni < 4; ++ni) acc[mi][ni] = (f32x4){0.f, 0.f, 0.f, 0.f};

#pragma unroll
    for (int kk = 0; kk < 8; ++kk) {
      f16x8 bF[4];
#pragma unroll
      for (int ni = 0; ni < 4; ++ni)
        bF[ni] = *(const f16x8*)&Bs[cur][(ni * 16 + rl) * 256 + (((kk * 4 + kc) ^ rl) << 3)];
#pragma unroll
      for (int mi = 0; mi < 2; ++mi)
#pragma unroll
        for (int ni = 0; ni < 4; ++ni)
          acc[mi][ni] = __builtin_amdgcn_mfma_f32_16x16x32_f16(aF[mi][kk], bF[ni], acc[mi][ni], 0, 0, 0);
    }

    float asv[4], adv[4];
#pragma unroll
    for (int ni = 0; ni < 4; ++ni) {
      asv[ni] = att_s_g[cb0 + ni * 16 + rl];
      adv[ni] = att_d_g[cb0 + ni * 16 + rl];
    }
#pragma unroll
    for (int mi = 0; mi < 2; ++mi)
#pragma unroll
      for (int j = 0; j < 4; ++j) {
        int row = row0 + mi * 16 + kc * 4 + j;
        bool ok = row < NR;
        float ps = 0.f, pd = 0.f, pr = 0.f;
#pragma unroll
        for (int ni = 0; ni < 4; ++ni) {
          float v = acc[mi][ni][j];
          ps += v * asv[ni];
          pd += v * adv[ni];
          pr += v;
          if (ok) C[(size_t)row * 1024 + cb0 + ni * 16 + rl] = f2h(v);
        }
        as_run[mi][j] += ps; ad_run[mi][j] += pd; sr_run[mi][j] += pr;
      }
    if ((hn & 3) == 3) {
      const int h = hn >> 2;
#pragma unroll
      for (int mi = 0; mi < 2; ++mi)
#pragma unroll
        for (int j = 0; j < 4; ++j) {
          float ps = as_run[mi][j], pd = ad_run[mi][j], pr = sr_run[mi][j];
#pragma unroll
          for (int o = 1; o <= 8; o <<= 1) {
            ps += __shfl_xor(ps, o);
            pd += __shfl_xor(pd, o);
            pr += __shfl_xor(pr, o);
          }
          if (rl == 0) {
            int row = row0 + mi * 16 + kc * 4 + j;
            if (row < NR) {
              a_s[(size_t)row * 4 + h] = ps;
              a_d[(size_t)row * 4 + h] = pd;
              s_row[(size_t)row * 4 + h] = pr;
            }
          }
          as_run[mi][j] = 0.f; ad_run[mi][j] = 0.f; sr_run[mi][j] = 0.f;
        }
    }
    __syncthreads();
  }
}

// ---------------- per-edge denom + numerator + CSR scatter (merged) ----------------
__global__ __launch_bounds__(256) void k_denom(const int* __restrict__ ei, const int* __restrict__ rowstart,
                                               int* __restrict__ cursor,
                                               const float* __restrict__ a_s, const float* __restrict__ a_d,
                                               const float* __restrict__ s_row,
                                               float* __restrict__ denom, float* __restrict__ num,
                                               float* __restrict__ pe_csr, float* __restrict__ pe_self,
                                               int* __restrict__ csr_src,
                                               int E, int n) {
  int e = blockIdx.x * 256 + threadIdx.x;
  int tot = E + n;
  if (e >= tot) return;
  int src = e < E ? ei[e] : (e - E);
  int dst = e < E ? ei[E + e] : (e - E);
  float asv[4], adv[4], sv[4], pv[4];
  *(float4*)asv = *(const float4*)(a_s + (size_t)src * 4);
  *(float4*)adv = *(const float4*)(a_d + (size_t)dst * 4);
  *(float4*)sv = *(const float4*)(s_row + (size_t)src * 4);
#pragma unroll
  for (int h = 0; h < 4; ++h) {
    float p = expf(lrelu(asv[h] + adv[h]));
    pv[h] = p;
    atomicAdd(&denom[(size_t)dst * 4 + h], p);
    atomicAdd(&num[(size_t)dst * 4 + h], p * sv[h]);
  }
  if (e < E) {
    int pos = rowstart[dst] + atomicAdd(&cursor[dst], 1);
    csr_src[pos] = src;
    *(float4*)(pe_csr + (size_t)pos * 4) = *(float4*)pv;
  } else {
    *(float4*)(pe_self + (size_t)(e - E) * 4) = *(float4*)pv;
  }
}

// ---------------- pooled[h] = sum_dst num/denom ----------------
__global__ __launch_bounds__(256) void k_pool2(const float* __restrict__ denom,
                                               const float* __restrict__ num,
                                               float* __restrict__ pooled, int n) {
  float ph[4] = {0.f, 0.f, 0.f, 0.f};
  for (int i = blockIdx.x * 256 + threadIdx.x; i < n; i += gridDim.x * 256) {
    float4 dv = *(const float4*)(denom + (size_t)i * 4);
    float4 nv = *(const float4*)(num + (size_t)i * 4);
    ph[0] += nv.x / (dv.x + 1e-16f);
    ph[1] += nv.y / (dv.y + 1e-16f);
    ph[2] += nv.z / (dv.z + 1e-16f);
    ph[3] += nv.w / (dv.w + 1e-16f);
  }
  int w = threadIdx.x >> 6, lane = threadIdx.x & 63;
#pragma unroll
  for (int h = 0; h < 4; ++h)
#pragma unroll
    for (int o = 32; o >= 1; o >>= 1) ph[h] += __shfl_xor(ph[h], o);
  __shared__ float red[4][4];
  if (lane == 0) {
#pragma unroll
    for (int h = 0; h < 4; ++h) red[w][h] = ph[h];
  }
  __syncthreads();
  if (threadIdx.x == 0) {
#pragma unroll
    for (int h = 0; h < 4; ++h)
      atomicAdd(&pooled[h], red[0][h] + red[1][h] + red[2][h] + red[3][h]);
  }
}

// ---------------- head gate + fused bias ----------------
__global__ __launch_bounds__(256) void k_head(const float* __restrict__ pooled,
                                              const float* __restrict__ gbias,
                                              const float* __restrict__ cw, const float* __restrict__ cb,
                                              float* __restrict__ a4, float* __restrict__ hb, int n) {
  __shared__ float red[4][4];
  __shared__ float aa[4];
  int t = threadIdx.x, w = t >> 6, lane = t & 63;
#pragma unroll
  for (int h = 0; h < 4; ++h) {
    float v = gbias[h * 256 + t];
#pragma unroll
    for (int o = 32; o >= 1; o >>= 1) v += __shfl_xor(v, o);
    if (lane == 0) red[h][w] = v;
  }
  __syncthreads();
  if (t == 0) {
    float q[4], mx = -1e30f;
    for (int h = 0; h < 4; ++h) {
      float bm = (red[h][0] + red[h][1] + red[h][2] + red[h][3]) * (1.f / 256.f);
      float pl = pooled[h] / ((float)n * 256.f) + bm;
      float c = pl * cw[0] + cb[0];
      c = fmaxf(c, 0.f);
      q[h] = c;
      mx = fmaxf(mx, c);
    }
    float sum = 0.f;
    for (int h = 0; h < 4; ++h) { q[h] = expf(q[h] - mx); sum += q[h]; }
    for (int h = 0; h < 4; ++h) { aa[h] = q[h] / sum; a4[h] = aa[h]; }
  }
  __syncthreads();
  float hbv = 0.f;
  for (int h = 0; h < 4; ++h) hbv += aa[h] * gbias[h * 256 + t];
  hb[t] = hbv;
}

// ---------------- per-node fused aggregation -> h (fp16 out), CSR ----------------
__global__ __launch_bounds__(256) void k_fuse(const int* __restrict__ rowstart,
                                              const int* __restrict__ csr_src,
                                              const unsigned short* __restrict__ xwh,
                                              const float* __restrict__ pe_csr,
                                              const float* __restrict__ pe_self,
                                              const float* __restrict__ denom,
                                              const float* __restrict__ a4, const float* __restrict__ hb,
                                              const float* __restrict__ x, unsigned short* __restrict__ hbuf,
                                              int n) {
  int node = blockIdx.x * 4 + (threadIdx.x >> 6);
  int lane = threadIdx.x & 63;
  if (node >= n) return;
  float dv[4], av[4], avinv[4];
  *(float4*)dv = *(const float4*)(denom + (size_t)node * 4);
  *(float4*)av = *(const float4*)a4;
#pragma unroll
  for (int h = 0; h < 4; ++h) avinv[h] = av[h] / (dv[h] + 1e-16f);
  float acc0 = 0.f, acc1 = 0.f, acc2 = 0.f, acc3 = 0.f;
  const int c0 = lane * 4;

  {
    float pv[4];
    *(float4*)pv = *(const float4*)(pe_self + (size_t)node * 4);
    float ws[4];
#pragma unroll
    for (int h = 0; h < 4; ++h) ws[h] = avinv[h] * pv[h];
    const unsigned short* rp = xwh + (size_t)node * 1024;
#pragma unroll
    for (int h = 0; h < 4; ++h) {
      u16x4 q = *(const u16x4*)(rp + h * 256 + c0);
      acc0 += ws[h] * h2f(q[0]);
      acc1 += ws[h] * h2f(q[1]);
      acc2 += ws[h] * h2f(q[2]);
      acc3 += ws[h] * h2f(q[3]);
    }
  }

  const int s0 = rowstart[node], s1 = rowstart[node + 1];
  int i = s0;
  int jn = 0;
  float4 pvn = {0.f, 0.f, 0.f, 0.f};
  if (i < s1) {
    jn = csr_src[i];
    pvn = *(const float4*)(pe_csr + (size_t)i * 4);
  }
  while (i < s1) {
    int j = jn;
    float4 pv4 = pvn;
    int i2 = i + 1;
    if (i2 < s1) {
      jn = csr_src[i2];
      pvn = *(const float4*)(pe_csr + (size_t)i2 * 4);
    }
    float ws[4];
    ws[0] = avinv[0] * pv4.x; ws[1] = avinv[1] * pv4.y;
    ws[2] = avinv[2] * pv4.z; ws[3] = avinv[3] * pv4.w;
    const unsigned short* rp = xwh + (size_t)j * 1024;
#pragma unroll
    for (int h = 0; h < 4; ++h) {
      u16x4 q = *(const u16x4*)(rp + h * 256 + c0);
      acc0 += ws[h] * h2f(q[0]);
      acc1 += ws[h] * h2f(q[1]);
      acc2 += ws[h] * h2f(q[2]);
      acc3 += ws[h] * h2f(q[3]);
    }
    i = i2;
  }
  float4 xb = *(const float4*)(x + (size_t)node * 256 + c0);
  float4 hbv = *(const float4*)(hb + c0);
  u16x4 o;
  o[0] = f2h(fmaxf(acc0 + hbv.x + xb.x, 0.f));
  o[1] = f2h(fmaxf(acc1 + hbv.y + xb.y, 0.f));
  o[2] = f2h(fmaxf(acc2 + hbv.z + xb.z, 0.f));
  o[3] = f2h(fmaxf(acc3 + hbv.w + xb.w, 0.f));
  *(u16x4*)(hbuf + (size_t)node * 256 + c0) = o;
}

// ---------------- edge classifier + log_softmax (fp16 gather) ----------------
__global__ __launch_bounds__(256) void k_out(const int* __restrict__ ei,
                                             const unsigned short* __restrict__ hbuf,
                                             const float* __restrict__ linW, const float* __restrict__ linb,
                                             float* __restrict__ out, int E) {
  int gw = blockIdx.x * 4 + (threadIdx.x >> 6);
  int lane = threadIdx.x & 63;
  if (gw >= E) return;
  int src = ei[gw], dst = ei[E + gw];
  const int c0 = lane * 4;
  u16x4 qs = *(const u16x4*)(hbuf + (size_t)src * 256 + c0);
  u16x4 qd = *(const u16x4*)(hbuf + (size_t)dst * 256 + c0);
  float4 wa = *(const float4*)(linW + (size_t)c0 * 2);
  float4 wb = *(const float4*)(linW + (size_t)c0 * 2 + 4);
  float e0 = h2f(qs[0]) * h2f(qd[0]);
  float e1 = h2f(qs[1]) * h2f(qd[1]);
  float e2 = h2f(qs[2]) * h2f(qd[2]);
  float e3 = h2f(qs[3]) * h2f(qd[3]);
  float u0 = e0 * wa.x + e1 * wa.z + e2 * wb.x + e3 * wb.z;
  float u1 = e0 * wa.y + e1 * wa.w + e2 * wb.y + e3 * wb.w;
#pragma unroll
  for (int o = 32; o >= 1; o >>= 1) {
    u0 += __shfl_xor(u0, o);
    u1 += __shfl_xor(u1, o);
  }
  if (lane == 0) {
    u0 += linb[0];
    u1 += linb[1];
    float mx = fmaxf(u0, u1);
    float lse = mx + logf(expf(u0 - mx) + expf(u1 - mx));
    float2 r;
    r.x = u0 - lse;
    r.y = u1 - lse;
    *(float2*)(out + (size_t)gw * 2) = r;
  }
}

// ---------------- launch ----------------
extern "C" void kernel_launch(void* const* d_in, const int* in_sizes, int n_in,
                              void* d_out, int out_size, void* d_ws, size_t ws_size,
                              hipStream_t stream) {
  const float* x = (const float*)d_in[0];
  const int* ei = (const int*)d_in[1];
  const float* W = (const float*)d_in[2];
  const float* att_s_g = (const float*)d_in[3];
  const float* att_d_g = (const float*)d_in[4];
  const float* gbias = (const float*)d_in[5];
  const float* cw = (const float*)d_in[6];
  const float* cb = (const float*)d_in[7];
  const float* linW = (const float*)d_in[8];
  const float* linb = (const float*)d_in[9];
  float* out = (float*)d_out;

  const int n = in_sizes[0] / 256;   // 100000
  const int E = in_sizes[1] / 2;     // 300000
  const int tot = E + n;
  const int nb = (n + 255) / 256;

  char* p = (char*)d_ws;
  auto alloc = [&](size_t bytes) -> char* {
    char* r = p;
    p += (bytes + 255) & ~(size_t)255;
    return r;
  };
  unsigned short* xwh = (unsigned short*)alloc((size_t)n * 1024 * 2);
  unsigned short* wth = (unsigned short*)alloc((size_t)1024 * 256 * 2);
  float* a_s = (float*)alloc((size_t)n * 4 * 4);
  float* a_d = (float*)alloc((size_t)n * 4 * 4);
  float* s_row = (float*)alloc((size_t)n * 4 * 4);
  float* denom = (float*)alloc((size_t)n * 4 * 4);
  float* num = (float*)alloc((size_t)n * 4 * 4);
  float* pe_csr = (float*)alloc((size_t)E * 4 * 4);
  float* pe_self = (float*)alloc((size_t)n * 4 * 4);
  int* deg = (int*)alloc((size_t)n * 4);
  int* cursor = (int*)alloc((size_t)n * 4);
  int* pre = (int*)alloc((size_t)n * 4);
  int* bsum = (int*)alloc(512 * 4);
  int* bsumx = (int*)alloc(512 * 4);
  int* rowstart = (int*)alloc((size_t)(n + 1) * 4);
  int* csr_src = (int*)alloc((size_t)E * 4);
  float* pooled = (float*)alloc(256);
  float* a4 = (float*)alloc(256);
  float* hb = (float*)alloc(256 * 4);
  unsigned short* hbuf = (unsigned short*)alloc((size_t)n * 256 * 2);

  k_wt<<<dim3(1024), dim3(256), 0, stream>>>(W, wth);
  k_init<<<dim3((n * 4 + 255) / 256), dim3(256), 0, stream>>>(denom, num, deg, cursor, pooled, n);
  k_count<<<dim3((E + 255) / 256), dim3(256), 0, stream>>>(ei, deg, E);
  k_scan1<<<dim3(nb), dim3(256), 0, stream>>>(deg, pre, bsum, n);
  k_scan2<<<dim3(1), dim3(256), 0, stream>>>(bsum, bsumx, nb);
  k_scan3<<<dim3(nb), dim3(256), 0, stream>>>(pre, bsumx, rowstart, n, E);
  k_gemm<<<dim3((n + 127) / 128), dim3(256), 0, stream>>>(x, wth, att_s_g, att_d_g, xwh, a_s, a_d, s_row, n);
  k_denom<<<dim3((tot + 255) / 256), dim3(256), 0, stream>>>(ei, rowstart, cursor, a_s, a_d, s_row, denom, num, pe_csr, pe_self, csr_src, E, n);
  k_pool2<<<dim3(64), dim3(256), 0, stream>>>(denom, num, pooled, n);
  k_head<<<dim3(1), dim3(256), 0, stream>>>(pooled, gbias, cw, cb, a4, hb, n);
  k_fuse<<<dim3((n + 3) / 4), dim3(256), 0, stream>>>(rowstart, csr_src, xwh, pe_csr, pe_self, denom, a4, hb, x, hbuf, n);
  k_out<<<dim3((E + 3) / 4), dim3(256), 0, stream>>>(ei, hbuf, linW, linb, out, E);
}

// Round 18
// 404.530 us; speedup vs baseline: 1.5314x; 1.2702x over previous
//
#include <hip/hip_runtime.h>
#include <stdint.h>
#include <stddef.h>

// Pipeline:
//  k_wt     : W -> Wt fp16 [1024][256] (transposed)
//  k_init   : deg=cursor=0, pooled=0
//  k_count  : deg[dst]++ over edges
//  k_scan1/2/3 : exclusive scan of deg -> rowstart[n+1]  (CSR offsets)
//  k_gemm   : 256 thr / 4 waves, BLK_M=128, B strips of 64 cols dbuf in LDS
//             (2x32KB). R14 config (143us verified; bigger-footprint variants
//             thrash L3). f16 MFMA; A frags in regs; xw fp16.
//  k_edge   : p=exp(lrelu(a_s[src]+a_d[dst])); CSR scatter only
//             (1 cursor atomic + plain stores). R17's merged k_denom did 3.6M
//             memory-side fp32 atomics -> 150us serialization; now ZERO.
//  k_nodesum: thread per node: stream contiguous pe_csr row + L2 s_row gather
//             -> denom[node] plain store; pooled += num/denom via block reduce.
//             (absorbs k_pool2)
//  k_head   : head gate a4 + fused bias hb
//  k_fuse   : per node (1 wave): CSR loop, (j,pv) prefetched 1 ahead. h fp16.
//  k_out    : per edge (1 wave): log_softmax((h[s]*h[d]) @ linW + b)

typedef _Float16 f16x8 __attribute__((ext_vector_type(8)));
typedef float f32x4 __attribute__((ext_vector_type(4)));
typedef unsigned short u16x8 __attribute__((ext_vector_type(8)));
typedef unsigned short u16x4 __attribute__((ext_vector_type(4)));

__device__ __forceinline__ unsigned short f2h(float f) {
  _Float16 h = (_Float16)f;
  return __builtin_bit_cast(unsigned short, h);
}
__device__ __forceinline__ float h2f(unsigned short s) {
  return (float)__builtin_bit_cast(_Float16, s);
}
__device__ __forceinline__ float lrelu(float v) { return v >= 0.f ? v : 0.2f * v; }

__device__ __forceinline__ void gload16(const void* g, void* l) {
  __builtin_amdgcn_global_load_lds((const __attribute__((address_space(1))) void*)g,
                                   (__attribute__((address_space(3))) void*)l, 16, 0, 0);
}

// ---------------- weight transpose ----------------
__global__ __launch_bounds__(256) void k_wt(const float* __restrict__ W,
                                            unsigned short* __restrict__ wt) {
  int idx = blockIdx.x * 256 + threadIdx.x;
  int m = idx >> 8, k = idx & 255;
  wt[idx] = f2h(W[(size_t)k * 1024 + m]);
}

// ---------------- init ----------------
__global__ __launch_bounds__(256) void k_init(int* __restrict__ deg, int* __restrict__ cursor,
                                              float* __restrict__ pooled, int n) {
  int i = blockIdx.x * 256 + threadIdx.x;
  if (i < n) { deg[i] = 0; cursor[i] = 0; }
  if (i < 4) pooled[i] = 0.f;
}

// ---------------- CSR build ----------------
__global__ __launch_bounds__(256) void k_count(const int* __restrict__ ei, int* __restrict__ deg, int E) {
  int e = blockIdx.x * 256 + threadIdx.x;
  if (e < E) atomicAdd(&deg[ei[E + e]], 1);
}

__global__ __launch_bounds__(256) void k_scan1(const int* __restrict__ deg, int* __restrict__ pre,
                                               int* __restrict__ bsum, int n) {
  int t = threadIdx.x, b = blockIdx.x;
  int i = b * 256 + t;
  int v = (i < n) ? deg[i] : 0;
  int lane = t & 63, w = t >> 6;
  int incl = v;
#pragma unroll
  for (int o = 1; o < 64; o <<= 1) {
    int u = __shfl_up(incl, o);
    if (lane >= o) incl += u;
  }
  __shared__ int ws[4];
  if (lane == 63) ws[w] = incl;
  __syncthreads();
  int add = 0;
  for (int k = 0; k < w; ++k) add += ws[k];
  int excl = incl - v + add;
  if (i < n) pre[i] = excl;
  if (t == 255) bsum[b] = excl + v;
}

__global__ __launch_bounds__(256) void k_scan2(const int* __restrict__ bsum, int* __restrict__ bsumx, int nb) {
  __shared__ int s[2][512];
  int t = threadIdx.x;
#pragma unroll
  for (int k = 0; k < 2; ++k) {
    int i = t + 256 * k;
    s[0][i] = (i < nb) ? bsum[i] : 0;
  }
  __syncthreads();
  int src = 0;
  for (int off = 1; off < 512; off <<= 1) {
#pragma unroll
    for (int k = 0; k < 2; ++k) {
      int i = t + 256 * k;
      int v = s[src][i];
      if (i >= off) v += s[src][i - off];
      s[src ^ 1][i] = v;
    }
    __syncthreads();
    src ^= 1;
  }
#pragma unroll
  for (int k = 0; k < 2; ++k) {
    int i = t + 256 * k;
    if (i < nb) bsumx[i] = s[src][i] - bsum[i];
  }
}

__global__ __launch_bounds__(256) void k_scan3(const int* __restrict__ pre, const int* __restrict__ bsumx,
                                               int* __restrict__ rowstart, int n, int E) {
  int i = blockIdx.x * 256 + threadIdx.x;
  if (i < n) rowstart[i] = pre[i] + bsumx[blockIdx.x];
  if (i == 0) rowstart[n] = E;
}

// ---------------- GEMM: xw = x @ W (f16 MFMA), R14 config ----------------
__global__ __launch_bounds__(256, 2) void k_gemm(const float* __restrict__ X,
                                                 const unsigned short* __restrict__ Bt,
                                                 const float* __restrict__ att_s_g,
                                                 const float* __restrict__ att_d_g,
                                                 unsigned short* __restrict__ C,
                                                 float* __restrict__ a_s, float* __restrict__ a_d,
                                                 float* __restrict__ s_row,
                                                 int NR) {
  __shared__ unsigned short Bs[2][64 * 256];  // 2 x 32 KB
  const int t = threadIdx.x;
  const int w = t >> 6, lane = t & 63;
  const int kc = lane >> 4, rl = lane & 15;
  const int row0 = blockIdx.x * 128 + w * 32;

  f16x8 aF[2][8];
#pragma unroll
  for (int mi = 0; mi < 2; ++mi) {
    const int ar = min(row0 + mi * 16 + rl, NR - 1);
#pragma unroll
    for (int kk = 0; kk < 8; ++kk) {
      const float* xp = X + (size_t)ar * 256 + kk * 32 + kc * 8;
      float4 lo = *(const float4*)xp;
      float4 hi = *(const float4*)(xp + 4);
      f16x8 v;
      v[0] = (_Float16)lo.x; v[1] = (_Float16)lo.y;
      v[2] = (_Float16)lo.z; v[3] = (_Float16)lo.w;
      v[4] = (_Float16)hi.x; v[5] = (_Float16)hi.y;
      v[6] = (_Float16)hi.z; v[7] = (_Float16)hi.w;
      aF[mi][kk] = v;
    }
  }

#pragma unroll
  for (int i = 0; i < 8; ++i) {
    int idx = i * 256 + t;
    int r = idx >> 5, c = idx & 31;
    gload16(Bt + (size_t)r * 256 + ((c ^ (r & 15)) << 3),
            &Bs[0][(size_t)(i * 256 + w * 64) * 8]);
  }
  __syncthreads();

  float as_run[2][4], ad_run[2][4], sr_run[2][4];
#pragma unroll
  for (int mi = 0; mi < 2; ++mi)
#pragma unroll
    for (int j = 0; j < 4; ++j) { as_run[mi][j] = 0.f; ad_run[mi][j] = 0.f; sr_run[mi][j] = 0.f; }

#pragma unroll 1
  for (int hn = 0; hn < 16; ++hn) {
    const int cb0 = hn * 64;
    const int cur = hn & 1;
    if (hn < 15) {
#pragma unroll
      for (int i = 0; i < 8; ++i) {
        int idx = i * 256 + t;
        int r = idx >> 5, c = idx & 31;
        gload16(Bt + (size_t)(cb0 + 64 + r) * 256 + ((c ^ (r & 15)) << 3),
                &Bs[cur ^ 1][(size_t)(i * 256 + w * 64) * 8]);
      }
    }

    f32x4 acc[2][4];
#pragma unroll
    for (int mi = 0; mi < 2; ++mi)
#pragma unroll
      for (int ni = 0; ni < 4; ++ni) acc[mi][ni] = (f32x4){0.f, 0.f, 0.f, 0.f};

#pragma unroll
    for (int kk = 0; kk < 8; ++kk) {
      f16x8 bF[4];
#pragma unroll
      for (int ni = 0; ni < 4; ++ni)
        bF[ni] = *(const f16x8*)&Bs[cur][(ni * 16 + rl) * 256 + (((kk * 4 + kc) ^ rl) << 3)];
#pragma unroll
      for (int mi = 0; mi < 2; ++mi)
#pragma unroll
        for (int ni = 0; ni < 4; ++ni)
          acc[mi][ni] = __builtin_amdgcn_mfma_f32_16x16x32_f16(aF[mi][kk], bF[ni], acc[mi][ni], 0, 0, 0);
    }

    float asv[4], adv[4];
#pragma unroll
    for (int ni = 0; ni < 4; ++ni) {
      asv[ni] = att_s_g[cb0 + ni * 16 + rl];
      adv[ni] = att_d_g[cb0 + ni * 16 + rl];
    }
#pragma unroll
    for (int mi = 0; mi < 2; ++mi)
#pragma unroll
      for (int j = 0; j < 4; ++j) {
        int row = row0 + mi * 16 + kc * 4 + j;
        bool ok = row < NR;
        float ps = 0.f, pd = 0.f, pr = 0.f;
#pragma unroll
        for (int ni = 0; ni < 4; ++ni) {
          float v = acc[mi][ni][j];
          ps += v * asv[ni];
          pd += v * adv[ni];
          pr += v;
          if (ok) C[(size_t)row * 1024 + cb0 + ni * 16 + rl] = f2h(v);
        }
        as_run[mi][j] += ps; ad_run[mi][j] += pd; sr_run[mi][j] += pr;
      }
    if ((hn & 3) == 3) {
      const int h = hn >> 2;
#pragma unroll
      for (int mi = 0; mi < 2; ++mi)
#pragma unroll
        for (int j = 0; j < 4; ++j) {
          float ps = as_run[mi][j], pd = ad_run[mi][j], pr = sr_run[mi][j];
#pragma unroll
          for (int o = 1; o <= 8; o <<= 1) {
            ps += __shfl_xor(ps, o);
            pd += __shfl_xor(pd, o);
            pr += __shfl_xor(pr, o);
          }
          if (rl == 0) {
            int row = row0 + mi * 16 + kc * 4 + j;
            if (row < NR) {
              a_s[(size_t)row * 4 + h] = ps;
              a_d[(size_t)row * 4 + h] = pd;
              s_row[(size_t)row * 4 + h] = pr;
            }
          }
          as_run[mi][j] = 0.f; ad_run[mi][j] = 0.f; sr_run[mi][j] = 0.f;
        }
    }
    __syncthreads();
  }
}

// ---------------- per-edge p + CSR scatter (NO fp32 atomics) ----------------
__global__ __launch_bounds__(256) void k_edge(const int* __restrict__ ei, const int* __restrict__ rowstart,
                                              int* __restrict__ cursor,
                                              const float* __restrict__ a_s, const float* __restrict__ a_d,
                                              float* __restrict__ pe_csr, float* __restrict__ pe_self,
                                              int* __restrict__ csr_src,
                                              int E, int n) {
  int e = blockIdx.x * 256 + threadIdx.x;
  int tot = E + n;
  if (e >= tot) return;
  int src = e < E ? ei[e] : (e - E);
  int dst = e < E ? ei[E + e] : (e - E);
  float asv[4], adv[4], pv[4];
  *(float4*)asv = *(const float4*)(a_s + (size_t)src * 4);
  *(float4*)adv = *(const float4*)(a_d + (size_t)dst * 4);
#pragma unroll
  for (int h = 0; h < 4; ++h) pv[h] = expf(lrelu(asv[h] + adv[h]));
  if (e < E) {
    int pos = rowstart[dst] + atomicAdd(&cursor[dst], 1);
    csr_src[pos] = src;
    *(float4*)(pe_csr + (size_t)pos * 4) = *(float4*)pv;
  } else {
    *(float4*)(pe_self + (size_t)(e - E) * 4) = *(float4*)pv;
  }
}

// ---------------- per-node denom + pooled (streaming CSR, plain stores) ----------------
__global__ __launch_bounds__(256) void k_nodesum(const int* __restrict__ rowstart,
                                                 const int* __restrict__ csr_src,
                                                 const float* __restrict__ pe_csr,
                                                 const float* __restrict__ pe_self,
                                                 const float* __restrict__ s_row,
                                                 float* __restrict__ denom,
                                                 float* __restrict__ pooled, int n) {
  int node = blockIdx.x * 256 + threadIdx.x;
  float ph[4] = {0.f, 0.f, 0.f, 0.f};
  if (node < n) {
    float den[4], nm[4], pv[4], sv[4];
    *(float4*)pv = *(const float4*)(pe_self + (size_t)node * 4);
    *(float4*)sv = *(const float4*)(s_row + (size_t)node * 4);
#pragma unroll
    for (int h = 0; h < 4; ++h) { den[h] = pv[h]; nm[h] = pv[h] * sv[h]; }
    const int s0 = rowstart[node], s1 = rowstart[node + 1];
    for (int i = s0; i < s1; ++i) {
      int src = csr_src[i];
      *(float4*)pv = *(const float4*)(pe_csr + (size_t)i * 4);
      *(float4*)sv = *(const float4*)(s_row + (size_t)src * 4);
#pragma unroll
      for (int h = 0; h < 4; ++h) { den[h] += pv[h]; nm[h] += pv[h] * sv[h]; }
    }
    *(float4*)(denom + (size_t)node * 4) = *(float4*)den;
#pragma unroll
    for (int h = 0; h < 4; ++h) ph[h] = nm[h] / (den[h] + 1e-16f);
  }
  int w = threadIdx.x >> 6, lane = threadIdx.x & 63;
#pragma unroll
  for (int h = 0; h < 4; ++h)
#pragma unroll
    for (int o = 32; o >= 1; o >>= 1) ph[h] += __shfl_xor(ph[h], o);
  __shared__ float red[4][4];
  if (lane == 0) {
#pragma unroll
    for (int h = 0; h < 4; ++h) red[w][h] = ph[h];
  }
  __syncthreads();
  if (threadIdx.x == 0) {
#pragma unroll
    for (int h = 0; h < 4; ++h)
      atomicAdd(&pooled[h], red[0][h] + red[1][h] + red[2][h] + red[3][h]);
  }
}

// ---------------- head gate + fused bias ----------------
__global__ __launch_bounds__(256) void k_head(const float* __restrict__ pooled,
                                              const float* __restrict__ gbias,
                                              const float* __restrict__ cw, const float* __restrict__ cb,
                                              float* __restrict__ a4, float* __restrict__ hb, int n) {
  __shared__ float red[4][4];
  __shared__ float aa[4];
  int t = threadIdx.x, w = t >> 6, lane = t & 63;
#pragma unroll
  for (int h = 0; h < 4; ++h) {
    float v = gbias[h * 256 + t];
#pragma unroll
    for (int o = 32; o >= 1; o >>= 1) v += __shfl_xor(v, o);
    if (lane == 0) red[h][w] = v;
  }
  __syncthreads();
  if (t == 0) {
    float q[4], mx = -1e30f;
    for (int h = 0; h < 4; ++h) {
      float bm = (red[h][0] + red[h][1] + red[h][2] + red[h][3]) * (1.f / 256.f);
      float pl = pooled[h] / ((float)n * 256.f) + bm;
      float c = pl * cw[0] + cb[0];
      c = fmaxf(c, 0.f);
      q[h] = c;
      mx = fmaxf(mx, c);
    }
    float sum = 0.f;
    for (int h = 0; h < 4; ++h) { q[h] = expf(q[h] - mx); sum += q[h]; }
    for (int h = 0; h < 4; ++h) { aa[h] = q[h] / sum; a4[h] = aa[h]; }
  }
  __syncthreads();
  float hbv = 0.f;
  for (int h = 0; h < 4; ++h) hbv += aa[h] * gbias[h * 256 + t];
  hb[t] = hbv;
}

// ---------------- per-node fused aggregation -> h (fp16 out), CSR ----------------
__global__ __launch_bounds__(256) void k_fuse(const int* __restrict__ rowstart,
                                              const int* __restrict__ csr_src,
                                              const unsigned short* __restrict__ xwh,
                                              const float* __restrict__ pe_csr,
                                              const float* __restrict__ pe_self,
                                              const float* __restrict__ denom,
                                              const float* __restrict__ a4, const float* __restrict__ hb,
                                              const float* __restrict__ x, unsigned short* __restrict__ hbuf,
                                              int n) {
  int node = blockIdx.x * 4 + (threadIdx.x >> 6);
  int lane = threadIdx.x & 63;
  if (node >= n) return;
  float dv[4], av[4], avinv[4];
  *(float4*)dv = *(const float4*)(denom + (size_t)node * 4);
  *(float4*)av = *(const float4*)a4;
#pragma unroll
  for (int h = 0; h < 4; ++h) avinv[h] = av[h] / (dv[h] + 1e-16f);
  float acc0 = 0.f, acc1 = 0.f, acc2 = 0.f, acc3 = 0.f;
  const int c0 = lane * 4;

  {
    float pv[4];
    *(float4*)pv = *(const float4*)(pe_self + (size_t)node * 4);
    float ws[4];
#pragma unroll
    for (int h = 0; h < 4; ++h) ws[h] = avinv[h] * pv[h];
    const unsigned short* rp = xwh + (size_t)node * 1024;
#pragma unroll
    for (int h = 0; h < 4; ++h) {
      u16x4 q = *(const u16x4*)(rp + h * 256 + c0);
      acc0 += ws[h] * h2f(q[0]);
      acc1 += ws[h] * h2f(q[1]);
      acc2 += ws[h] * h2f(q[2]);
      acc3 += ws[h] * h2f(q[3]);
    }
  }

  const int s0 = rowstart[node], s1 = rowstart[node + 1];
  int i = s0;
  int jn = 0;
  float4 pvn = {0.f, 0.f, 0.f, 0.f};
  if (i < s1) {
    jn = csr_src[i];
    pvn = *(const float4*)(pe_csr + (size_t)i * 4);
  }
  while (i < s1) {
    int j = jn;
    float4 pv4 = pvn;
    int i2 = i + 1;
    if (i2 < s1) {
      jn = csr_src[i2];
      pvn = *(const float4*)(pe_csr + (size_t)i2 * 4);
    }
    float ws[4];
    ws[0] = avinv[0] * pv4.x; ws[1] = avinv[1] * pv4.y;
    ws[2] = avinv[2] * pv4.z; ws[3] = avinv[3] * pv4.w;
    const unsigned short* rp = xwh + (size_t)j * 1024;
#pragma unroll
    for (int h = 0; h < 4; ++h) {
      u16x4 q = *(const u16x4*)(rp + h * 256 + c0);
      acc0 += ws[h] * h2f(q[0]);
      acc1 += ws[h] * h2f(q[1]);
      acc2 += ws[h] * h2f(q[2]);
      acc3 += ws[h] * h2f(q[3]);
    }
    i = i2;
  }
  float4 xb = *(const float4*)(x + (size_t)node * 256 + c0);
  float4 hbv = *(const float4*)(hb + c0);
  u16x4 o;
  o[0] = f2h(fmaxf(acc0 + hbv.x + xb.x, 0.f));
  o[1] = f2h(fmaxf(acc1 + hbv.y + xb.y, 0.f));
  o[2] = f2h(fmaxf(acc2 + hbv.z + xb.z, 0.f));
  o[3] = f2h(fmaxf(acc3 + hbv.w + xb.w, 0.f));
  *(u16x4*)(hbuf + (size_t)node * 256 + c0) = o;
}

// ---------------- edge classifier + log_softmax (fp16 gather) ----------------
__global__ __launch_bounds__(256) void k_out(const int* __restrict__ ei,
                                             const unsigned short* __restrict__ hbuf,
                                             const float* __restrict__ linW, const float* __restrict__ linb,
                                             float* __restrict__ out, int E) {
  int gw = blockIdx.x * 4 + (threadIdx.x >> 6);
  int lane = threadIdx.x & 63;
  if (gw >= E) return;
  int src = ei[gw], dst = ei[E + gw];
  const int c0 = lane * 4;
  u16x4 qs = *(const u16x4*)(hbuf + (size_t)src * 256 + c0);
  u16x4 qd = *(const u16x4*)(hbuf + (size_t)dst * 256 + c0);
  float4 wa = *(const float4*)(linW + (size_t)c0 * 2);
  float4 wb = *(const float4*)(linW + (size_t)c0 * 2 + 4);
  float e0 = h2f(qs[0]) * h2f(qd[0]);
  float e1 = h2f(qs[1]) * h2f(qd[1]);
  float e2 = h2f(qs[2]) * h2f(qd[2]);
  float e3 = h2f(qs[3]) * h2f(qd[3]);
  float u0 = e0 * wa.x + e1 * wa.z + e2 * wb.x + e3 * wb.z;
  float u1 = e0 * wa.y + e1 * wa.w + e2 * wb.y + e3 * wb.w;
#pragma unroll
  for (int o = 32; o >= 1; o >>= 1) {
    u0 += __shfl_xor(u0, o);
    u1 += __shfl_xor(u1, o);
  }
  if (lane == 0) {
    u0 += linb[0];
    u1 += linb[1];
    float mx = fmaxf(u0, u1);
    float lse = mx + logf(expf(u0 - mx) + expf(u1 - mx));
    float2 r;
    r.x = u0 - lse;
    r.y = u1 - lse;
    *(float2*)(out + (size_t)gw * 2) = r;
  }
}

// ---------------- launch ----------------
extern "C" void kernel_launch(void* const* d_in, const int* in_sizes, int n_in,
                              void* d_out, int out_size, void* d_ws, size_t ws_size,
                              hipStream_t stream) {
  const float* x = (const float*)d_in[0];
  const int* ei = (const int*)d_in[1];
  const float* W = (const float*)d_in[2];
  const float* att_s_g = (const float*)d_in[3];
  const float* att_d_g = (const float*)d_in[4];
  const float* gbias = (const float*)d_in[5];
  const float* cw = (const float*)d_in[6];
  const float* cb = (const float*)d_in[7];
  const float* linW = (const float*)d_in[8];
  const float* linb = (const float*)d_in[9];
  float* out = (float*)d_out;

  const int n = in_sizes[0] / 256;   // 100000
  const int E = in_sizes[1] / 2;     // 300000
  const int tot = E + n;
  const int nb = (n + 255) / 256;

  char* p = (char*)d_ws;
  auto alloc = [&](size_t bytes) -> char* {
    char* r = p;
    p += (bytes + 255) & ~(size_t)255;
    return r;
  };
  unsigned short* xwh = (unsigned short*)alloc((size_t)n * 1024 * 2);
  unsigned short* wth = (unsigned short*)alloc((size_t)1024 * 256 * 2);
  float* a_s = (float*)alloc((size_t)n * 4 * 4);
  float* a_d = (float*)alloc((size_t)n * 4 * 4);
  float* s_row = (float*)alloc((size_t)n * 4 * 4);
  float* denom = (float*)alloc((size_t)n * 4 * 4);
  float* pe_csr = (float*)alloc((size_t)E * 4 * 4);
  float* pe_self = (float*)alloc((size_t)n * 4 * 4);
  int* deg = (int*)alloc((size_t)n * 4);
  int* cursor = (int*)alloc((size_t)n * 4);
  int* pre = (int*)alloc((size_t)n * 4);
  int* bsum = (int*)alloc(512 * 4);
  int* bsumx = (int*)alloc(512 * 4);
  int* rowstart = (int*)alloc((size_t)(n + 1) * 4);
  int* csr_src = (int*)alloc((size_t)E * 4);
  float* pooled = (float*)alloc(256);
  float* a4 = (float*)alloc(256);
  float* hb = (float*)alloc(256 * 4);
  unsigned short* hbuf = (unsigned short*)alloc((size_t)n * 256 * 2);

  k_wt<<<dim3(1024), dim3(256), 0, stream>>>(W, wth);
  k_init<<<dim3(nb), dim3(256), 0, stream>>>(deg, cursor, pooled, n);
  k_count<<<dim3((E + 255) / 256), dim3(256), 0, stream>>>(ei, deg, E);
  k_scan1<<<dim3(nb), dim3(256), 0, stream>>>(deg, pre, bsum, n);
  k_scan2<<<dim3(1), dim3(256), 0, stream>>>(bsum, bsumx, nb);
  k_scan3<<<dim3(nb), dim3(256), 0, stream>>>(pre, bsumx, rowstart, n, E);
  k_gemm<<<dim3((n + 127) / 128), dim3(256), 0, stream>>>(x, wth, att_s_g, att_d_g, xwh, a_s, a_d, s_row, n);
  k_edge<<<dim3((tot + 255) / 256), dim3(256), 0, stream>>>(ei, rowstart, cursor, a_s, a_d, pe_csr, pe_self, csr_src, E, n);
  k_nodesum<<<dim3(nb), dim3(256), 0, stream>>>(rowstart, csr_src, pe_csr, pe_self, s_row, denom, pooled, n);
  k_head<<<dim3(1), dim3(256), 0, stream>>>(pooled, gbias, cw, cb, a4, hb, n);
  k_fuse<<<dim3((n + 3) / 4), dim3(256), 0, stream>>>(rowstart, csr_src, xwh, pe_csr, pe_self, denom, a4, hb, x, hbuf, n);
  k_out<<<dim3((E + 3) / 4), dim3(256), 0, stream>>>(ei, hbuf, linW, linb, out, E);
}